// Round 1
// baseline (333.395 us; speedup 1.0000x reference)
//
#include <hip/hip_runtime.h>

// CharAttention: per (b,w) causal char-attention, but only the row at
// x_end_idx[b,w] survives the final gather -- so compute ONLY that row.
//
//   B=512, W=128, C_BLK=24, C=32, H=2, D=16.
//   q = x[qidx] @ Wq (1x32); k,v = x[0..qidx] @ Wk,Wv (Lx32);
//   s[h][j] = (q_h . k_j,h)/4, softmax over j<=qidx; o = p @ v;
//   out = x[qidx] + o @ Wproj.
//
// One wave (64-thread block) per (b,w). 65,536 blocks.

#define CB     24
#define CC     32
#define NH     2
#define DD     16
#define THREEC 96

__global__ __launch_bounds__(64, 4) void char_attn_kernel(
    const float* __restrict__ x,        // [B*W, 24, 32]
    const int*   __restrict__ xend,     // [B*W]
    const float* __restrict__ w_attn,   // [32, 96]
    const float* __restrict__ w_proj,   // [32, 32]
    float*       __restrict__ out)      // [B*W, 32]
{
    __shared__ float xs[CB][CC];        // staged x rows (3072 B)
    __shared__ float ks[CB][CC + 1];    // k, padded stride 33 for j-strided reads
    __shared__ float qs[CC];
    __shared__ float ps[NH][32];        // softmax probs
    __shared__ float os[CC];            // attention output row

    const int bid  = blockIdx.x;
    const int lane = threadIdx.x;       // 0..63
    const float* xb = x + (size_t)bid * (CB * CC);
    const int qidx = xend[bid];         // 0..23
    const int L    = qidx + 1;

    // ---- stage x rows 0..L-1 into LDS (coalesced float4) ----
    {
        const float4* xb4 = (const float4*)xb;
        float4* xs4 = (float4*)&xs[0][0];
        const int n4 = L * (CC / 4);    // <= 144
        for (int t = lane; t < n4; t += 64) xs4[t] = xb4[t];
    }

    // ---- this lane's k/v column of w_attn in registers ----
    // lane<32: k col lane = w_attn[:,32+lane]; lane>=32: v col (lane-32) = w_attn[:,32+lane].
    float wkv[CC];
    #pragma unroll
    for (int c = 0; c < CC; ++c) wkv[c] = w_attn[c * THREEC + 32 + lane];

    __syncthreads();

    // ---- kv = xs[0..L-1] @ w_attn[:,32:96]; k -> LDS, v -> registers ----
    float vreg[CB];
    #pragma unroll
    for (int j = 0; j < CB; ++j) {
        if (j < L) {                            // wave-uniform guard
            const float4* row = (const float4*)&xs[j][0];   // broadcast reads
            float acc = 0.f;
            #pragma unroll
            for (int c4 = 0; c4 < CC / 4; ++c4) {
                float4 r = row[c4];
                acc += r.x * wkv[c4 * 4 + 0];
                acc += r.y * wkv[c4 * 4 + 1];
                acc += r.z * wkv[c4 * 4 + 2];
                acc += r.w * wkv[c4 * 4 + 3];
            }
            if (lane < CC) ks[j][lane] = acc;
            else           vreg[j]    = acc;
        }
    }

    // ---- q row (lanes 0..31): q[i] = dot(xs[qidx], w_attn[:,i]) ----
    if (lane < CC) {
        const float4* row = (const float4*)&xs[qidx][0];
        float acc = 0.f;
        #pragma unroll
        for (int c4 = 0; c4 < CC / 4; ++c4) {
            float4 r = row[c4];
            acc += r.x * w_attn[(c4 * 4 + 0) * THREEC + lane];
            acc += r.y * w_attn[(c4 * 4 + 1) * THREEC + lane];
            acc += r.z * w_attn[(c4 * 4 + 2) * THREEC + lane];
            acc += r.w * w_attn[(c4 * 4 + 3) * THREEC + lane];
        }
        qs[lane] = acc;
    }

    __syncthreads();

    // ---- scores + softmax: lane -> (h = lane>>5, j = lane&31) ----
    {
        const int h = lane >> 5;
        const int j = lane & 31;
        float s = -INFINITY;
        if (j <= qidx) {                    // j <= 23
            float acc = 0.f;
            #pragma unroll
            for (int d = 0; d < DD; ++d)
                acc += qs[h * DD + d] * ks[j][h * DD + d];
            s = acc * 0.25f;                // 1/sqrt(16)
        }
        float m = s;                        // max over the 32-lane half
        #pragma unroll
        for (int off = 16; off >= 1; off >>= 1)
            m = fmaxf(m, __shfl_xor(m, off));
        float e = (j <= qidx) ? __expf(s - m) : 0.f;
        float sum = e;
        #pragma unroll
        for (int off = 16; off >= 1; off >>= 1)
            sum += __shfl_xor(sum, off);
        ps[h][j] = e / sum;
    }

    __syncthreads();

    // ---- att @ v (lanes 32..63 hold v columns in registers) ----
    if (lane >= CC) {
        const int dp = lane - CC;           // output dim 0..31
        const int h  = dp >> 4;             // head
        float acc = 0.f;
        #pragma unroll
        for (int j = 0; j < CB; ++j)
            if (j < L) acc += ps[h][j] * vreg[j];
        os[dp] = acc;
    }

    __syncthreads();

    // ---- proj + residual + store (lanes 32..63) ----
    if (lane >= CC) {
        const int i = lane - CC;
        float acc = xs[qidx][i];            // residual
        #pragma unroll
        for (int c = 0; c < CC; ++c)
            acc += os[c] * w_proj[c * CC + i];
        out[(size_t)bid * CC + i] = acc;
    }
}

extern "C" void kernel_launch(void* const* d_in, const int* in_sizes, int n_in,
                              void* d_out, int out_size, void* d_ws, size_t ws_size,
                              hipStream_t stream) {
    const float* x      = (const float*)d_in[0];
    const int*   xend   = (const int*)d_in[1];
    const float* w_attn = (const float*)d_in[2];
    const float* w_proj = (const float*)d_in[3];
    float* out = (float*)d_out;

    const int nbw = 512 * 128;              // B * W
    char_attn_kernel<<<dim3(nbw), dim3(64), 0, stream>>>(x, xend, w_attn, w_proj, out);
}